// Round 15
// baseline (223.362 us; speedup 1.0000x reference)
//
#include <hip/hip_runtime.h>
#include <hip/hip_bf16.h>
#include <stdint.h>

// B=2, S=2048, H=16, Dk=Dv=64, D_MODEL=1024.
// d_out = out[2*2048*1024] fp32  ++  attn[2*16*2048*2048] fp32.

typedef __attribute__((ext_vector_type(8))) __bf16 bf16x8;
typedef __attribute__((ext_vector_type(4))) float f32x4;

#define GLDS16(gp, lp)                                                        \
  __builtin_amdgcn_global_load_lds(                                           \
      (const __attribute__((address_space(1))) void*)(gp),                    \
      (__attribute__((address_space(3))) void*)(lp), 16, 0, 0)

// softmax shift in exp2 domain: 8 * log2(e)
#define SH2 11.5416928f

__device__ __forceinline__ ushort f2b(float f) {  // fp32 -> bf16 bits (RNE)
  __bf16 b = (__bf16)f;
  return __builtin_bit_cast(ushort, b);
}
__device__ __forceinline__ float b2f(ushort u) {  // bf16 bits -> fp32
  return __uint_as_float(((uint32_t)u) << 16);
}

// --- 1024x1024 transpose+convert: W[in][out] -> Wt[out][in], z=0..3 --------
__global__ __launch_bounds__(256) void k_trcvt4(
    const float* __restrict__ a, const float* __restrict__ b,
    const float* __restrict__ c, const float* __restrict__ d,
    ushort* __restrict__ ao, ushort* __restrict__ bo, ushort* __restrict__ co,
    ushort* __restrict__ eo) {
  const int z = blockIdx.z;
  const float* in = (z == 0) ? a : (z == 1) ? b : (z == 2) ? c : d;
  ushort* out = (z == 0) ? ao : (z == 1) ? bo : (z == 2) ? co : eo;
  __shared__ float tile[32][33];
  int j0 = blockIdx.x * 32, i0 = blockIdx.y * 32;
  int tx = threadIdx.x & 31, ty = threadIdx.x >> 5;
#pragma unroll
  for (int p = 0; p < 4; ++p)
    tile[ty + p * 8][tx] = in[(size_t)(i0 + ty + p * 8) * 1024 + j0 + tx];
  __syncthreads();
#pragma unroll
  for (int p = 0; p < 4; ++p)
    out[(size_t)(j0 + ty + p * 8) * 1024 + i0 + tx] = f2b(tile[tx][ty + p * 8]);
}

// ---- shared bf16 MFMA GEMM core: C = A[M][K]*B[N][K]^T, tile (MB*32)x128 ---
template <int MB>  // MB=2 -> 64x128 tile (FC)
__device__ __forceinline__ void gemm_core(const ushort* __restrict__ A,
                                          const ushort* __restrict__ B, int K,
                                          int m0, int n0, ushort* As,
                                          ushort* Bs, f32x4 (&acc)[MB][4]) {
  const int l = threadIdx.x & 63, w = threadIdx.x >> 6;
  const int g = l >> 4, r16 = l & 15;
  const int wm = (w >> 1) * (MB * 16), wn = (w & 1) * 64;
  const int wbase = w * 64;
  for (int k0 = 0; k0 < K; k0 += 64) {
    __syncthreads();
#pragma unroll
    for (int c = 0; c < MB; ++c) {  // A: MB*64 rows * 64 cols
      int ub = c * 256 + wbase;
      int li = ub + l;
      int row = li >> 3;
      int sl = (li & 7) ^ (row & 7);
      GLDS16(A + (size_t)(m0 + row) * K + k0 + sl * 8, &As[ub * 8]);
    }
#pragma unroll
    for (int c = 0; c < 4; ++c) {  // B: 128 rows * 64 cols
      int ub = c * 256 + wbase;
      int li = ub + l;
      int row = li >> 3;
      int sl = (li & 7) ^ (row & 7);
      GLDS16(B + (size_t)(n0 + row) * K + k0 + sl * 8, &Bs[ub * 8]);
    }
    __syncthreads();
#pragma unroll
    for (int kk = 0; kk < 2; ++kk) {
      bf16x8 af[MB], bfr[4];
#pragma unroll
      for (int i = 0; i < MB; ++i) {
        int rowA = wm + i * 16 + r16;
        int slA = (kk * 4 + g) ^ (rowA & 7);
        af[i] = *(const bf16x8*)&As[rowA * 64 + slA * 8];
      }
#pragma unroll
      for (int j = 0; j < 4; ++j) {
        int rowB = wn + j * 16 + r16;
        int slB = (kk * 4 + g) ^ (rowB & 7);
        bfr[j] = *(const bf16x8*)&Bs[rowB * 64 + slB * 8];
      }
#pragma unroll
      for (int i = 0; i < MB; ++i)
#pragma unroll
        for (int j = 0; j < 4; ++j)
          acc[i][j] = __builtin_amdgcn_mfma_f32_16x16x32_bf16(
              af[i], bfr[j], acc[i][j], 0, 0, 0);
    }
  }
}

// ---- mixed-precision 128x128 core: one operand fp32 (reg-staged + cvt +
// prefetch across counted-vmcnt barrier), the other bf16 via GLDS16. --------
template <bool AF32, bool BF32>
__device__ __forceinline__ void qkv_core(const void* Avp, const void* Bvp,
                                         int m0, int n0, ushort* As,
                                         ushort* Bs, f32x4 (&acc)[4][4]) {
  constexpr int K = 1024;
  const int tid = threadIdx.x;
  const int l = tid & 63, w = tid >> 6;
  const int g = l >> 4, r16 = l & 15;
  const int wm = (w >> 1) * 64, wn = (w & 1) * 64;
  const int wbase = w * 64;
  const float* Af = (const float*)Avp;
  const ushort* Ab = (const ushort*)Avp;
  const float* Bf = (const float*)Bvp;
  const ushort* Bb = (const ushort*)Bvp;
  // fp32-staging geometry: 128 rows x 8 slots (8 bf16 each); 4 per thread.
  int srow[4], sj[4];
#pragma unroll
  for (int c = 0; c < 4; ++c) {
    int idx = c * 256 + tid;
    srow[c] = idx >> 3;
    sj[c] = idx & 7;
  }
  float4 pf[4][2];
  // prologue: prefetch fp32 tile 0 into regs
#pragma unroll
  for (int c = 0; c < 4; ++c) {
    const float* p = AF32 ? (Af + (size_t)(m0 + srow[c]) * K + sj[c] * 8)
                          : (Bf + (size_t)(n0 + srow[c]) * K + sj[c] * 8);
    pf[c][0] = ((const float4*)p)[0];
    pf[c][1] = ((const float4*)p)[1];
  }
  for (int k0 = 0; k0 < K; k0 += 64) {
    __syncthreads();
    // fp32 operand: regs -> bf16 -> swizzled ds_write_b128
    {
      ushort* dst = AF32 ? As : Bs;
#pragma unroll
      for (int c = 0; c < 4; ++c) {
        union {
          bf16x8 v;
          ushort u[8];
        } pk;
        const float* f0 = (const float*)&pf[c][0];
#pragma unroll
        for (int j2 = 0; j2 < 8; ++j2) pk.u[j2] = f2b(f0[j2]);
        *(bf16x8*)&dst[srow[c] * 64 + (sj[c] ^ (srow[c] & 7)) * 8] = pk.v;
      }
    }
    // bf16 operand: 4x GLDS16 (these must be the OLDEST vmem ops this iter)
    {
      const ushort* src = AF32 ? Bb : Ab;
      const int base0 = AF32 ? n0 : m0;
      ushort* dst = AF32 ? Bs : As;
#pragma unroll
      for (int c = 0; c < 4; ++c) {
        int ub = c * 256 + wbase;
        int li = ub + l, row = li >> 3, sl = (li & 7) ^ (row & 7);
        GLDS16(src + (size_t)(base0 + row) * K + k0 + sl * 8, &dst[ub * 8]);
      }
    }
    __builtin_amdgcn_sched_barrier(0);  // pin GLDS before prefetch loads
    const bool pfed = (k0 + 64 < K);
    if (pfed) {  // prefetch next fp32 tile; stays in flight across barrier
#pragma unroll
      for (int c = 0; c < 4; ++c) {
        const float* p =
            AF32 ? (Af + (size_t)(m0 + srow[c]) * K + (k0 + 64) + sj[c] * 8)
                 : (Bf + (size_t)(n0 + srow[c]) * K + (k0 + 64) + sj[c] * 8);
        pf[c][0] = ((const float4*)p)[0];
        pf[c][1] = ((const float4*)p)[1];
      }
      __builtin_amdgcn_sched_barrier(0);
      // retire the 4 GLDS (oldest) + all ds_writes; 8 prefetch loads fly on
      asm volatile("s_waitcnt vmcnt(8) lgkmcnt(0)" ::: "memory");
    } else {
      asm volatile("s_waitcnt vmcnt(0) lgkmcnt(0)" ::: "memory");
    }
    __builtin_amdgcn_s_barrier();
    __builtin_amdgcn_sched_barrier(0);
    // compute
#pragma unroll
    for (int kk = 0; kk < 2; ++kk) {
      bf16x8 af[4], bfr[4];
#pragma unroll
      for (int i = 0; i < 4; ++i) {
        int rowA = wm + i * 16 + r16;
        int slA = (kk * 4 + g) ^ (rowA & 7);
        af[i] = *(const bf16x8*)&As[rowA * 64 + slA * 8];
      }
#pragma unroll
      for (int j = 0; j < 4; ++j) {
        int rowB = wn + j * 16 + r16;
        int slB = (kk * 4 + g) ^ (rowB & 7);
        bfr[j] = *(const bf16x8*)&Bs[rowB * 64 + slB * 8];
      }
#pragma unroll
      for (int i = 0; i < 4; ++i)
#pragma unroll
        for (int j = 0; j < 4; ++j)
          acc[i][j] = __builtin_amdgcn_mfma_f32_16x16x32_bf16(
              af[i], bfr[j], acc[i][j], 0, 0, 0);
    }
  }
}

// ---- fused QKV projection, fp32 inputs consumed directly ------------------
__global__ __launch_bounds__(256, 3) void k_gemm_qkv(
    const float* __restrict__ q, const float* __restrict__ k,
    const float* __restrict__ v, const ushort* __restrict__ Wq,
    const ushort* __restrict__ Wk, const ushort* __restrict__ Wv,
    ushort* __restrict__ Qh, ushort* __restrict__ Kh,
    ushort* __restrict__ Vt) {
  __shared__ __align__(16) ushort As[8192];
  __shared__ __align__(16) ushort Bs[8192];
  const int z = blockIdx.y;
  const int bx = (blockIdx.x & 7) * 32 + (blockIdx.x >> 3);  // XCD swizzle
  int m0, n0;
  if (z < 2) {
    m0 = (bx >> 3) * 128;  // M=4096 (q/k rows)
    n0 = (bx & 7) * 128;   // N=1024 (W out-cols)
  } else {
    m0 = (bx >> 5) * 128;  // M=1024 (Wv rows)
    n0 = (bx & 31) * 128;  // N=4096 (v rows)
  }
  f32x4 acc[4][4] = {};
  if (z == 0)
    qkv_core<true, false>(q, Wq, m0, n0, As, Bs, acc);
  else if (z == 1)
    qkv_core<true, false>(k, Wk, m0, n0, As, Bs, acc);
  else
    qkv_core<false, true>(Wv, v, m0, n0, As, Bs, acc);
  const int l = threadIdx.x & 63, w = threadIdx.x >> 6;
  const int g = l >> 4, r16 = l & 15;
  const int wm = (w >> 1) * 64, wn = (w & 1) * 64;
  // Q is pre-scaled by (1/8)*log2(e) so attn uses exp2 directly.
  const float scale = (z == 0) ? 0.125f * 1.44269504f : 1.0f;
  ushort* C = (z == 0) ? Qh : (z == 1) ? Kh : Vt;
#pragma unroll
  for (int i = 0; i < 4; ++i)
#pragma unroll
    for (int j = 0; j < 4; ++j)
#pragma unroll
      for (int r = 0; r < 4; ++r) {
        int rr = m0 + wm + i * 16 + g * 4 + r;
        int cc = n0 + wn + j * 16 + r16;
        float val = acc[i][j][r] * scale;
        if (z < 2) {  // [b][h][s][d]
          int b = rr >> 11, s = rr & 2047, h = cc >> 6, dd = cc & 63;
          C[(((size_t)(b * 16 + h) * 2048 + s) << 6) + dd] = f2b(val);
        } else {  // [b][h][d][s]
          int h = rr >> 6, dd = rr & 63, b = cc >> 11, s = cc & 2047;
          C[(((size_t)(b * 16 + h) * 64 + dd) << 11) + s] = f2b(val);
        }
      }
}

// ------------------- FC: out = Op @ Wf  (fp32), 64x128 tiles ----------------
__global__ __launch_bounds__(256) void k_gemm_fc(const ushort* __restrict__ Op,
                                                 const ushort* __restrict__ Wf,
                                                 float* __restrict__ out) {
  __shared__ __align__(16) ushort As[4096];
  __shared__ __align__(16) ushort Bs[8192];
  const int bx = (blockIdx.x & 7) * 8 + (blockIdx.x >> 3);  // XCD swizzle (64)
  int m0 = bx * 64, n0 = blockIdx.y * 128;
  f32x4 acc[2][4] = {};
  gemm_core<2>(Op, Wf, 1024, m0, n0, As, Bs, acc);
  const int l = threadIdx.x & 63, w = threadIdx.x >> 6;
  const int g = l >> 4, r16 = l & 15;
  const int wm = (w >> 1) * 32, wn = (w & 1) * 64;
#pragma unroll
  for (int i = 0; i < 2; ++i)
#pragma unroll
    for (int j = 0; j < 4; ++j)
#pragma unroll
      for (int r = 0; r < 4; ++r)
        out[(size_t)(m0 + wm + i * 16 + g * 4 + r) * 1024 + n0 + wn + j * 16 +
            r16] = acc[i][j][r];
}

// ---- fused attention, high-occupancy: 1024 WGs x 64 q-rows (4 waves x 16).
// Phase A: denom, KVBLK=64 K dbuf (16 KB). Phase B: attn+PV, KVBLK=32
// K dbuf 8 KB + V dbuf 8 KB + Ps 5 KB. Peak LDS ~21 KB -> 4 WGs/CU,
// grid 1024 = 4*256 (zero tail), 4 waves/SIMD.
__global__ __launch_bounds__(256, 4) void k_attn_fused(
    const ushort* __restrict__ Q,   // [32][2048][64], scaled by log2e/8
    const ushort* __restrict__ Kh,  // [32][2048][64]
    const ushort* __restrict__ Vt,  // [32][64][2048]
    float* __restrict__ attn,       // [32][2048][2048]
    ushort* __restrict__ Op) {      // [4096][1024] bf16
  __shared__ __align__(16) ushort KVs[8192];       // 16 KB shared pool
  __shared__ __align__(16) ushort Ps[4][16 * 40];  // bf16 P, stride 40
  const int t = threadIdx.x, l = t & 63, w = t >> 6;
  const int g = l >> 4, r16 = l & 15;
  const int di = blockIdx.x;
  const int wid = (di & 7) * 128 + (di >> 3);  // XCD bijective (1024 = 8*128)
  const int bh = wid >> 5;                     // 32 WGs per head
  const int qw = (wid & 31) * 64 + w * 16;     // wave's 16 q-rows
  const size_t headQ = (size_t)bh * 2048;
  const int wbase = w * 64;

  bf16x8 qf[2];
  {
    const ushort* qp = Q + (headQ + qw + r16) * 64 + g * 8;
    qf[0] = *(const bf16x8*)qp;
    qf[1] = *(const bf16x8*)(qp + 32);
  }

  // ---------------- phase A: denominators, 64-row K tiles (dbuf) ----------
  float lsum[4] = {};
  {
    // stage tile 0 into buf 0: 2 chunks of 32 rows
#pragma unroll
    for (int c = 0; c < 2; ++c) {
      int li = c * 256 + t, row = li >> 3, sl = (li & 7) ^ (row & 7);
      GLDS16(Kh + (headQ + row) * 64 + sl * 8, &KVs[li * 8]);
    }
  }
  __syncthreads();
  int cur = 0;
  for (int kt = 0; kt < 32; ++kt) {
    if (kt < 31) {
      ushort* nb = KVs + (cur ^ 1) * 4096;
#pragma unroll
      for (int c = 0; c < 2; ++c) {
        int li = c * 256 + t, row = li >> 3, sl = (li & 7) ^ (row & 7);
        GLDS16(Kh + (headQ + (kt + 1) * 64 + row) * 64 + sl * 8, &nb[li * 8]);
      }
    }
    const ushort* kb = KVs + cur * 4096;
    __builtin_amdgcn_s_setprio(1);
    f32x4 sv[4];
#pragma unroll
    for (int jc = 0; jc < 4; ++jc) {
      f32x4 s = {0.f, 0.f, 0.f, 0.f};
      int rowK = jc * 16 + r16;
      int sa = g ^ (rowK & 7), sb = (4 + g) ^ (rowK & 7);
      s = __builtin_amdgcn_mfma_f32_16x16x32_bf16(
          qf[0], *(const bf16x8*)&kb[rowK * 64 + sa * 8], s, 0, 0, 0);
      s = __builtin_amdgcn_mfma_f32_16x16x32_bf16(
          qf[1], *(const bf16x8*)&kb[rowK * 64 + sb * 8], s, 0, 0, 0);
      sv[jc] = s;
    }
    __builtin_amdgcn_s_setprio(0);
#pragma unroll
    for (int jc = 0; jc < 4; ++jc)
#pragma unroll
      for (int r = 0; r < 4; ++r) lsum[r] += exp2f(sv[jc][r] - SH2);
    __syncthreads();
    cur ^= 1;
  }
  float il[4];
#pragma unroll
  for (int r = 0; r < 4; ++r) {
    float v = lsum[r];
    v += __shfl_xor(v, 1);
    v += __shfl_xor(v, 2);
    v += __shfl_xor(v, 4);
    v += __shfl_xor(v, 8);
    il[r] = 1.0f / v;
  }

  // ---------------- phase B: attn stores + PV, 32-row K/V tiles -----------
  // LDS: K dbuf KVs[0]/KVs[2048]; V dbuf KVs[4096]/KVs[6144].
  // K tile: [32 k][64 d], 8 slots/row, XOR-8 swizzle.
  // V tile: [64 d][32 k], 4 slots/row, XOR-4 swizzle.
  const int krow = t >> 3, ksl = (t & 7) ^ (krow & 7);
  const ushort* Kg = Kh + (headQ + krow) * 64 + ksl * 8;
  const int vrow = t >> 2, vsl = (t & 3) ^ (vrow & 3);
  const ushort* Vg = Vt + ((size_t)bh * 64 + vrow) * 2048 + vsl * 8;

  f32x4 o[4] = {};
  ushort* Pw = &Ps[w][0];
  GLDS16(Kg, &KVs[t * 8]);
  GLDS16(Vg, &KVs[4096 + t * 8]);
  asm volatile("s_waitcnt vmcnt(0)" ::: "memory");
  __builtin_amdgcn_s_barrier();
  __builtin_amdgcn_sched_barrier(0);
  cur = 0;
  for (int kt = 0; kt < 64; ++kt) {
    if (kt < 63) {  // prefetch next tile FIRST (oldest VMEM ops this iter)
      GLDS16(Kg + (kt + 1) * 2048, &KVs[(cur ^ 1) * 2048 + t * 8]);
      GLDS16(Vg + (kt + 1) * 32, &KVs[4096 + (cur ^ 1) * 2048 + t * 8]);
      __builtin_amdgcn_sched_barrier(0);  // pin GLDS before stores
    }
    const ushort* kb = KVs + cur * 2048;
    const ushort* vb = KVs + 4096 + cur * 2048;
    // QK^T: scores[16 q][32 k]
    __builtin_amdgcn_s_setprio(1);
    f32x4 sv[2];
#pragma unroll
    for (int jc = 0; jc < 2; ++jc) {
      f32x4 s = {0.f, 0.f, 0.f, 0.f};
      int rowK = jc * 16 + r16;
      int sa = g ^ (rowK & 7), sb = (4 + g) ^ (rowK & 7);
      s = __builtin_amdgcn_mfma_f32_16x16x32_bf16(
          qf[0], *(const bf16x8*)&kb[rowK * 64 + sa * 8], s, 0, 0, 0);
      s = __builtin_amdgcn_mfma_f32_16x16x32_bf16(
          qf[1], *(const bf16x8*)&kb[rowK * 64 + sb * 8], s, 0, 0, 0);
      sv[jc] = s;
    }
    __builtin_amdgcn_s_setprio(0);
    // normalized P -> LDS (bf16, stride 40)
#pragma unroll
    for (int jc = 0; jc < 2; ++jc)
#pragma unroll
      for (int r = 0; r < 4; ++r)
        Pw[(g * 4 + r) * 40 + jc * 16 + r16] =
            f2b(exp2f(sv[jc][r] - SH2) * il[r]);
    // PV: O[16 q][64 d] += P[16 q][32 k] * V[32 k][64 d]
    __builtin_amdgcn_s_setprio(1);
    {
      bf16x8 pf = *(const bf16x8*)&Pw[r16 * 40 + g * 8];
#pragma unroll
      for (int dc = 0; dc < 4; ++dc) {
        int rowV = dc * 16 + r16;
        int sl = g ^ (rowV & 3);
        o[dc] = __builtin_amdgcn_mfma_f32_16x16x32_bf16(
            pf, *(const bf16x8*)&vb[rowV * 32 + sl * 8], o[dc], 0, 0, 0);
      }
    }
    __builtin_amdgcn_s_setprio(0);
    // transpose-read rows -> widen bf16->f32 -> f32x4 nontemporal stores
#pragma unroll
    for (int p = 0; p < 2; ++p) {
      int row2 = p * 8 + (l >> 3);
      int j = l & 7;
      const ushort* pr = &Pw[row2 * 40 + j * 4];
      f32x4 pv = {b2f(pr[0]), b2f(pr[1]), b2f(pr[2]), b2f(pr[3])};
      __builtin_nontemporal_store(
          pv, (f32x4*)&attn[(headQ + qw + row2) * 2048 + kt * 32 + j * 4]);
    }
    if (kt < 63) {
      // counted vmcnt: retire this iter's 2 GLDS (+older stores); leave the
      // 2 newest nt-stores in flight across the barrier.
      asm volatile("s_waitcnt vmcnt(2)" ::: "memory");
      __builtin_amdgcn_s_barrier();
      __builtin_amdgcn_sched_barrier(0);
    }
    cur ^= 1;
  }

  const int b = bh >> 4, h = bh & 15;
#pragma unroll
  for (int dc = 0; dc < 4; ++dc)
#pragma unroll
    for (int r = 0; r < 4; ++r)
      Op[((size_t)(b * 2048 + qw + g * 4 + r)) * 1024 + h * 64 + dc * 16 +
         r16] = f2b(o[dc][r]);
}

// ---------------------------------------------------------------------------
extern "C" void kernel_launch(void* const* d_in, const int* in_sizes, int n_in,
                              void* d_out, int out_size, void* d_ws,
                              size_t ws_size, hipStream_t stream) {
  const float* q = (const float*)d_in[0];
  const float* k = (const float*)d_in[1];
  const float* v = (const float*)d_in[2];
  const float* w_qs = (const float*)d_in[3];
  const float* w_ks = (const float*)d_in[4];
  const float* w_vs = (const float*)d_in[5];
  const float* w_fc = (const float*)d_in[6];
  float* out = (float*)d_out;
  float* attn = out + (size_t)4096 * 1024;

  const size_t MB = 1024 * 1024;
  uint8_t* ws = (uint8_t*)d_ws;
  ushort* Qh = (ushort*)(ws + 0 * MB);   // [32][2048][64] bf16
  ushort* Kh = (ushort*)(ws + 8 * MB);   // [32][2048][64]
  ushort* Vt = (ushort*)(ws + 16 * MB);  // [32][64][2048]
  ushort* Op = (ushort*)(ws + 24 * MB);  // [4096][1024]
  ushort* Wq = (ushort*)(ws + 56 * MB);  // [1024 out][1024 in]
  ushort* Wk = (ushort*)(ws + 58 * MB);
  ushort* Wv = (ushort*)(ws + 60 * MB);
  ushort* Wf = (ushort*)(ws + 62 * MB);

  k_trcvt4<<<dim3(32, 32, 4), 256, 0, stream>>>(w_qs, w_ks, w_vs, w_fc, Wq, Wk,
                                                Wv, Wf);
  k_gemm_qkv<<<dim3(256, 3), 256, 0, stream>>>(q, k, v, Wq, Wk, Wv, Qh, Kh,
                                               Vt);
  k_attn_fused<<<1024, 256, 0, stream>>>(Qh, Kh, Vt, attn, Op);
  k_gemm_fc<<<dim3(64, 8), 256, 0, stream>>>(Op, Wf, out);
}

// Round 16
// 211.547 us; speedup vs baseline: 1.0559x; 1.0559x over previous
//
#include <hip/hip_runtime.h>
#include <hip/hip_bf16.h>
#include <stdint.h>

// B=2, S=2048, H=16, Dk=Dv=64, D_MODEL=1024.
// d_out = out[2*2048*1024] fp32  ++  attn[2*16*2048*2048] fp32.

typedef __attribute__((ext_vector_type(8))) __bf16 bf16x8;
typedef __attribute__((ext_vector_type(4))) float f32x4;

#define GLDS16(gp, lp)                                                        \
  __builtin_amdgcn_global_load_lds(                                           \
      (const __attribute__((address_space(1))) void*)(gp),                    \
      (__attribute__((address_space(3))) void*)(lp), 16, 0, 0)

// softmax shift in exp2 domain: 8 * log2(e)
#define SH2 11.5416928f

__device__ __forceinline__ ushort f2b(float f) {  // fp32 -> bf16 bits (RNE)
  __bf16 b = (__bf16)f;
  return __builtin_bit_cast(ushort, b);
}
__device__ __forceinline__ float b2f(ushort u) {  // bf16 bits -> fp32
  return __uint_as_float(((uint32_t)u) << 16);
}

// --- 1024x1024 transpose+convert: W[in][out] -> Wt[out][in], z=0..3 --------
__global__ __launch_bounds__(256) void k_trcvt4(
    const float* __restrict__ a, const float* __restrict__ b,
    const float* __restrict__ c, const float* __restrict__ d,
    ushort* __restrict__ ao, ushort* __restrict__ bo, ushort* __restrict__ co,
    ushort* __restrict__ eo) {
  const int z = blockIdx.z;
  const float* in = (z == 0) ? a : (z == 1) ? b : (z == 2) ? c : d;
  ushort* out = (z == 0) ? ao : (z == 1) ? bo : (z == 2) ? co : eo;
  __shared__ float tile[32][33];
  int j0 = blockIdx.x * 32, i0 = blockIdx.y * 32;
  int tx = threadIdx.x & 31, ty = threadIdx.x >> 5;
#pragma unroll
  for (int p = 0; p < 4; ++p)
    tile[ty + p * 8][tx] = in[(size_t)(i0 + ty + p * 8) * 1024 + j0 + tx];
  __syncthreads();
#pragma unroll
  for (int p = 0; p < 4; ++p)
    out[(size_t)(j0 + ty + p * 8) * 1024 + i0 + tx] = f2b(tile[tx][ty + p * 8]);
}

// ---- shared bf16 MFMA GEMM core: C = A[M][K]*B[N][K]^T, tile (MB*32)x128 ---
template <int MB>  // MB=2 -> 64x128 tile (FC)
__device__ __forceinline__ void gemm_core(const ushort* __restrict__ A,
                                          const ushort* __restrict__ B, int K,
                                          int m0, int n0, ushort* As,
                                          ushort* Bs, f32x4 (&acc)[MB][4]) {
  const int l = threadIdx.x & 63, w = threadIdx.x >> 6;
  const int g = l >> 4, r16 = l & 15;
  const int wm = (w >> 1) * (MB * 16), wn = (w & 1) * 64;
  const int wbase = w * 64;
  for (int k0 = 0; k0 < K; k0 += 64) {
    __syncthreads();
#pragma unroll
    for (int c = 0; c < MB; ++c) {  // A: MB*64 rows * 64 cols
      int ub = c * 256 + wbase;
      int li = ub + l;
      int row = li >> 3;
      int sl = (li & 7) ^ (row & 7);
      GLDS16(A + (size_t)(m0 + row) * K + k0 + sl * 8, &As[ub * 8]);
    }
#pragma unroll
    for (int c = 0; c < 4; ++c) {  // B: 128 rows * 64 cols
      int ub = c * 256 + wbase;
      int li = ub + l;
      int row = li >> 3;
      int sl = (li & 7) ^ (row & 7);
      GLDS16(B + (size_t)(n0 + row) * K + k0 + sl * 8, &Bs[ub * 8]);
    }
    __syncthreads();
#pragma unroll
    for (int kk = 0; kk < 2; ++kk) {
      bf16x8 af[MB], bfr[4];
#pragma unroll
      for (int i = 0; i < MB; ++i) {
        int rowA = wm + i * 16 + r16;
        int slA = (kk * 4 + g) ^ (rowA & 7);
        af[i] = *(const bf16x8*)&As[rowA * 64 + slA * 8];
      }
#pragma unroll
      for (int j = 0; j < 4; ++j) {
        int rowB = wn + j * 16 + r16;
        int slB = (kk * 4 + g) ^ (rowB & 7);
        bfr[j] = *(const bf16x8*)&Bs[rowB * 64 + slB * 8];
      }
#pragma unroll
      for (int i = 0; i < MB; ++i)
#pragma unroll
        for (int j = 0; j < 4; ++j)
          acc[i][j] = __builtin_amdgcn_mfma_f32_16x16x32_bf16(
              af[i], bfr[j], acc[i][j], 0, 0, 0);
    }
  }
}

// ---- mixed-precision 128x128 core: one operand fp32 (reg-staged + cvt +
// prefetch across counted-vmcnt barrier), the other bf16 via GLDS16. --------
template <bool AF32, bool BF32>
__device__ __forceinline__ void qkv_core(const void* Avp, const void* Bvp,
                                         int m0, int n0, ushort* As,
                                         ushort* Bs, f32x4 (&acc)[4][4]) {
  constexpr int K = 1024;
  const int tid = threadIdx.x;
  const int l = tid & 63, w = tid >> 6;
  const int g = l >> 4, r16 = l & 15;
  const int wm = (w >> 1) * 64, wn = (w & 1) * 64;
  const int wbase = w * 64;
  const float* Af = (const float*)Avp;
  const ushort* Ab = (const ushort*)Avp;
  const float* Bf = (const float*)Bvp;
  const ushort* Bb = (const ushort*)Bvp;
  // fp32-staging geometry: 128 rows x 8 slots (8 bf16 each); 4 per thread.
  int srow[4], sj[4];
#pragma unroll
  for (int c = 0; c < 4; ++c) {
    int idx = c * 256 + tid;
    srow[c] = idx >> 3;
    sj[c] = idx & 7;
  }
  float4 pf[4][2];
  // prologue: prefetch fp32 tile 0 into regs
#pragma unroll
  for (int c = 0; c < 4; ++c) {
    const float* p = AF32 ? (Af + (size_t)(m0 + srow[c]) * K + sj[c] * 8)
                          : (Bf + (size_t)(n0 + srow[c]) * K + sj[c] * 8);
    pf[c][0] = ((const float4*)p)[0];
    pf[c][1] = ((const float4*)p)[1];
  }
  for (int k0 = 0; k0 < K; k0 += 64) {
    __syncthreads();
    // fp32 operand: regs -> bf16 -> swizzled ds_write_b128
    {
      ushort* dst = AF32 ? As : Bs;
#pragma unroll
      for (int c = 0; c < 4; ++c) {
        union {
          bf16x8 v;
          ushort u[8];
        } pk;
        const float* f0 = (const float*)&pf[c][0];
#pragma unroll
        for (int j2 = 0; j2 < 8; ++j2) pk.u[j2] = f2b(f0[j2]);
        *(bf16x8*)&dst[srow[c] * 64 + (sj[c] ^ (srow[c] & 7)) * 8] = pk.v;
      }
    }
    // bf16 operand: 4x GLDS16 (these must be the OLDEST vmem ops this iter)
    {
      const ushort* src = AF32 ? Bb : Ab;
      const int base0 = AF32 ? n0 : m0;
      ushort* dst = AF32 ? Bs : As;
#pragma unroll
      for (int c = 0; c < 4; ++c) {
        int ub = c * 256 + wbase;
        int li = ub + l, row = li >> 3, sl = (li & 7) ^ (row & 7);
        GLDS16(src + (size_t)(base0 + row) * K + k0 + sl * 8, &dst[ub * 8]);
      }
    }
    __builtin_amdgcn_sched_barrier(0);  // pin GLDS before prefetch loads
    const bool pfed = (k0 + 64 < K);
    if (pfed) {  // prefetch next fp32 tile; stays in flight across barrier
#pragma unroll
      for (int c = 0; c < 4; ++c) {
        const float* p =
            AF32 ? (Af + (size_t)(m0 + srow[c]) * K + (k0 + 64) + sj[c] * 8)
                 : (Bf + (size_t)(n0 + srow[c]) * K + (k0 + 64) + sj[c] * 8);
        pf[c][0] = ((const float4*)p)[0];
        pf[c][1] = ((const float4*)p)[1];
      }
      __builtin_amdgcn_sched_barrier(0);
      // retire the 4 GLDS (oldest) + all ds_writes; 8 prefetch loads fly on
      asm volatile("s_waitcnt vmcnt(8) lgkmcnt(0)" ::: "memory");
    } else {
      asm volatile("s_waitcnt vmcnt(0) lgkmcnt(0)" ::: "memory");
    }
    __builtin_amdgcn_s_barrier();
    __builtin_amdgcn_sched_barrier(0);
    // compute
#pragma unroll
    for (int kk = 0; kk < 2; ++kk) {
      bf16x8 af[4], bfr[4];
#pragma unroll
      for (int i = 0; i < 4; ++i) {
        int rowA = wm + i * 16 + r16;
        int slA = (kk * 4 + g) ^ (rowA & 7);
        af[i] = *(const bf16x8*)&As[rowA * 64 + slA * 8];
      }
#pragma unroll
      for (int j = 0; j < 4; ++j) {
        int rowB = wn + j * 16 + r16;
        int slB = (kk * 4 + g) ^ (rowB & 7);
        bfr[j] = *(const bf16x8*)&Bs[rowB * 64 + slB * 8];
      }
#pragma unroll
      for (int i = 0; i < 4; ++i)
#pragma unroll
        for (int j = 0; j < 4; ++j)
          acc[i][j] = __builtin_amdgcn_mfma_f32_16x16x32_bf16(
              af[i], bfr[j], acc[i][j], 0, 0, 0);
    }
  }
}

// ---- fused QKV projection, fp32 inputs consumed directly ------------------
__global__ __launch_bounds__(256, 3) void k_gemm_qkv(
    const float* __restrict__ q, const float* __restrict__ k,
    const float* __restrict__ v, const ushort* __restrict__ Wq,
    const ushort* __restrict__ Wk, const ushort* __restrict__ Wv,
    ushort* __restrict__ Qh, ushort* __restrict__ Kh,
    ushort* __restrict__ Vt) {
  __shared__ __align__(16) ushort As[8192];
  __shared__ __align__(16) ushort Bs[8192];
  const int z = blockIdx.y;
  const int bx = (blockIdx.x & 7) * 32 + (blockIdx.x >> 3);  // XCD swizzle
  int m0, n0;
  if (z < 2) {
    m0 = (bx >> 3) * 128;  // M=4096 (q/k rows)
    n0 = (bx & 7) * 128;   // N=1024 (W out-cols)
  } else {
    m0 = (bx >> 5) * 128;  // M=1024 (Wv rows)
    n0 = (bx & 31) * 128;  // N=4096 (v rows)
  }
  f32x4 acc[4][4] = {};
  if (z == 0)
    qkv_core<true, false>(q, Wq, m0, n0, As, Bs, acc);
  else if (z == 1)
    qkv_core<true, false>(k, Wk, m0, n0, As, Bs, acc);
  else
    qkv_core<false, true>(Wv, v, m0, n0, As, Bs, acc);
  const int l = threadIdx.x & 63, w = threadIdx.x >> 6;
  const int g = l >> 4, r16 = l & 15;
  const int wm = (w >> 1) * 64, wn = (w & 1) * 64;
  // Q is pre-scaled by (1/8)*log2(e) so attn uses exp2 directly.
  const float scale = (z == 0) ? 0.125f * 1.44269504f : 1.0f;
  ushort* C = (z == 0) ? Qh : (z == 1) ? Kh : Vt;
#pragma unroll
  for (int i = 0; i < 4; ++i)
#pragma unroll
    for (int j = 0; j < 4; ++j)
#pragma unroll
      for (int r = 0; r < 4; ++r) {
        int rr = m0 + wm + i * 16 + g * 4 + r;
        int cc = n0 + wn + j * 16 + r16;
        float val = acc[i][j][r] * scale;
        if (z < 2) {  // [b][h][s][d]
          int b = rr >> 11, s = rr & 2047, h = cc >> 6, dd = cc & 63;
          C[(((size_t)(b * 16 + h) * 2048 + s) << 6) + dd] = f2b(val);
        } else {  // [b][h][d][s]
          int h = rr >> 6, dd = rr & 63, b = cc >> 11, s = cc & 2047;
          C[(((size_t)(b * 16 + h) * 64 + dd) << 11) + s] = f2b(val);
        }
      }
}

// ------------------- FC: out = Op @ Wf  (fp32), 64x128 tiles ----------------
__global__ __launch_bounds__(256) void k_gemm_fc(const ushort* __restrict__ Op,
                                                 const ushort* __restrict__ Wf,
                                                 float* __restrict__ out) {
  __shared__ __align__(16) ushort As[4096];
  __shared__ __align__(16) ushort Bs[8192];
  const int bx = (blockIdx.x & 7) * 8 + (blockIdx.x >> 3);  // XCD swizzle (64)
  int m0 = bx * 64, n0 = blockIdx.y * 128;
  f32x4 acc[2][4] = {};
  gemm_core<2>(Op, Wf, 1024, m0, n0, As, Bs, acc);
  const int l = threadIdx.x & 63, w = threadIdx.x >> 6;
  const int g = l >> 4, r16 = l & 15;
  const int wm = (w >> 1) * 32, wn = (w & 1) * 64;
#pragma unroll
  for (int i = 0; i < 2; ++i)
#pragma unroll
    for (int j = 0; j < 4; ++j)
#pragma unroll
      for (int r = 0; r < 4; ++r)
        out[(size_t)(m0 + wm + i * 16 + g * 4 + r) * 1024 + n0 + wn + j * 16 +
            r16] = acc[i][j][r];
}

// ---- fused attention: phase A denom (KVBLK=128) + phase B attn+PV ---------
// 512 WGs (all resident, zero tail): (bh, 128 q-rows), 4 waves x 32 rows.
__global__ __launch_bounds__(256, 2) void k_attn_fused(
    const ushort* __restrict__ Q,   // [32][2048][64], scaled by log2e/8
    const ushort* __restrict__ Kh,  // [32][2048][64]
    const ushort* __restrict__ Vt,  // [32][64][2048]
    float* __restrict__ attn,       // [32][2048][2048]
    ushort* __restrict__ Op) {      // [4096][1024] bf16
  __shared__ __align__(16) ushort KVs[16384];
  __shared__ __align__(16) ushort Ps[4][32 * 72];  // bf16 P, stride 72
  const int t = threadIdx.x, l = t & 63, w = t >> 6;
  const int g = l >> 4, r16 = l & 15;
  const int di = blockIdx.x;
  const int wid = (di & 7) * 64 + (di >> 3);  // XCD x owns heads [4x,4x+4)
  const int bh = wid >> 4;
  const int q0 = (wid & 15) * 128 + w * 32;
  const size_t headQ = (size_t)bh * 2048;
  const int wbase = w * 64;

  bf16x8 qf[2][2];
#pragma unroll
  for (int qi = 0; qi < 2; ++qi) {
    const ushort* qp = Q + (headQ + q0 + qi * 16 + r16) * 64 + g * 8;
    qf[qi][0] = *(const bf16x8*)qp;
    qf[qi][1] = *(const bf16x8*)(qp + 32);
  }

  // ---------------- phase A: denominators, 128-row K tiles ----------------
  float lsum[2][4] = {};
#pragma unroll
  for (int c = 0; c < 4; ++c) {  // stage tile 0 (128 rows) into buf 0
    int ub = c * 256 + wbase;
    int li = ub + l, row = li >> 3, sl = (li & 7) ^ (row & 7);
    GLDS16(Kh + (headQ + row) * 64 + sl * 8, &KVs[ub * 8]);
  }
  __syncthreads();
  int cur = 0;
  for (int kt = 0; kt < 16; ++kt) {
    if (kt < 15) {
      ushort* nb = KVs + (cur ^ 1) * 8192;
#pragma unroll
      for (int c = 0; c < 4; ++c) {
        int ub = c * 256 + wbase;
        int li = ub + l, row = li >> 3, sl = (li & 7) ^ (row & 7);
        GLDS16(Kh + (headQ + (kt + 1) * 128 + row) * 64 + sl * 8, &nb[ub * 8]);
      }
    }
    const ushort* kb = KVs + cur * 8192;
#pragma unroll
    for (int half = 0; half < 2; ++half) {
      __builtin_amdgcn_s_setprio(1);
      f32x4 sv[2][4];
#pragma unroll
      for (int qi = 0; qi < 2; ++qi)
#pragma unroll
        for (int jc = 0; jc < 4; ++jc) {
          f32x4 s = {0.f, 0.f, 0.f, 0.f};
          int rowK = (half * 4 + jc) * 16 + r16;
          int sa = g ^ (rowK & 7), sb = (4 + g) ^ (rowK & 7);
          s = __builtin_amdgcn_mfma_f32_16x16x32_bf16(
              qf[qi][0], *(const bf16x8*)&kb[rowK * 64 + sa * 8], s, 0, 0, 0);
          s = __builtin_amdgcn_mfma_f32_16x16x32_bf16(
              qf[qi][1], *(const bf16x8*)&kb[rowK * 64 + sb * 8], s, 0, 0, 0);
          sv[qi][jc] = s;
        }
      __builtin_amdgcn_s_setprio(0);
#pragma unroll
      for (int qi = 0; qi < 2; ++qi)
#pragma unroll
        for (int jc = 0; jc < 4; ++jc)
#pragma unroll
          for (int r = 0; r < 4; ++r) lsum[qi][r] += exp2f(sv[qi][jc][r] - SH2);
    }
    __syncthreads();
    cur ^= 1;
  }
  float il[2][4];
#pragma unroll
  for (int qi = 0; qi < 2; ++qi)
#pragma unroll
    for (int r = 0; r < 4; ++r) {
      float v = lsum[qi][r];
      v += __shfl_xor(v, 1);
      v += __shfl_xor(v, 2);
      v += __shfl_xor(v, 4);
      v += __shfl_xor(v, 8);
      il[qi][r] = 1.0f / v;
    }

  // ---------------- phase B: attn stores + PV (64-row K/V tiles) ----------
  const int li0 = wbase + l, row0 = li0 >> 3, sl0 = (li0 & 7) ^ (row0 & 7);
  const int li1 = 256 + wbase + l, row1 = li1 >> 3, sl1 = (li1 & 7) ^ (row1 & 7);
  const ushort* Kg0 = Kh + (headQ + row0) * 64 + sl0 * 8;
  const ushort* Kg1 = Kh + (headQ + row1) * 64 + sl1 * 8;
  const ushort* Vg0 = Vt + ((size_t)bh * 64 + row0) * 2048 + sl0 * 8;
  const ushort* Vg1 = Vt + ((size_t)bh * 64 + row1) * 2048 + sl1 * 8;

  f32x4 o[2][4] = {};
  ushort* Pw = &Ps[w][0];
  GLDS16(Kg0, &KVs[wbase * 8]);
  GLDS16(Kg1, &KVs[(256 + wbase) * 8]);
  GLDS16(Vg0, &KVs[8192 + wbase * 8]);
  GLDS16(Vg1, &KVs[8192 + (256 + wbase) * 8]);
  __syncthreads();
  cur = 0;
  for (int kt = 0; kt < 32; ++kt) {
    if (kt < 31) {  // prefetch next tile FIRST (oldest VMEM ops this iter)
      ushort* nK = KVs + (cur ^ 1) * 4096;
      ushort* nV = KVs + 8192 + (cur ^ 1) * 4096;
      GLDS16(Kg0 + (kt + 1) * 4096, &nK[wbase * 8]);
      GLDS16(Kg1 + (kt + 1) * 4096, &nK[(256 + wbase) * 8]);
      GLDS16(Vg0 + (kt + 1) * 64, &nV[wbase * 8]);
      GLDS16(Vg1 + (kt + 1) * 64, &nV[(256 + wbase) * 8]);
      __builtin_amdgcn_sched_barrier(0);  // pin GLDS before stores
    }
    const ushort* kb = KVs + cur * 4096;
    const ushort* vb = KVs + 8192 + cur * 4096;
    // QK^T
    __builtin_amdgcn_s_setprio(1);
    f32x4 sv[2][4];
#pragma unroll
    for (int qi = 0; qi < 2; ++qi)
#pragma unroll
      for (int jc = 0; jc < 4; ++jc) {
        f32x4 s = {0.f, 0.f, 0.f, 0.f};
        int rowK = jc * 16 + r16;
        int sa = g ^ (rowK & 7), sb = (4 + g) ^ (rowK & 7);
        s = __builtin_amdgcn_mfma_f32_16x16x32_bf16(
            qf[qi][0], *(const bf16x8*)&kb[rowK * 64 + sa * 8], s, 0, 0, 0);
        s = __builtin_amdgcn_mfma_f32_16x16x32_bf16(
            qf[qi][1], *(const bf16x8*)&kb[rowK * 64 + sb * 8], s, 0, 0, 0);
        sv[qi][jc] = s;
      }
    __builtin_amdgcn_s_setprio(0);
    // normalized P -> LDS (bf16)
#pragma unroll
    for (int qi = 0; qi < 2; ++qi)
#pragma unroll
      for (int jc = 0; jc < 4; ++jc)
#pragma unroll
        for (int r = 0; r < 4; ++r)
          Pw[(qi * 16 + g * 4 + r) * 72 + jc * 16 + r16] =
              f2b(exp2f(sv[qi][jc][r] - SH2) * il[qi][r]);
    // PV (bf16 A-fragments straight from Ps)
    __builtin_amdgcn_s_setprio(1);
#pragma unroll
    for (int qi = 0; qi < 2; ++qi)
#pragma unroll
      for (int kk = 0; kk < 2; ++kk) {
        bf16x8 pf = *(const bf16x8*)&Pw[(qi * 16 + r16) * 72 + kk * 32 + g * 8];
#pragma unroll
        for (int dc = 0; dc < 4; ++dc) {
          int rowV = dc * 16 + r16;
          int sl = (kk * 4 + g) ^ (rowV & 7);
          o[qi][dc] = __builtin_amdgcn_mfma_f32_16x16x32_bf16(
              pf, *(const bf16x8*)&vb[rowV * 64 + sl * 8], o[qi][dc], 0, 0, 0);
        }
      }
    __builtin_amdgcn_s_setprio(0);
    // transpose-read rows -> widen bf16->f32 -> dwordx4 nontemporal stores
#pragma unroll
    for (int qi = 0; qi < 2; ++qi)
#pragma unroll
      for (int i2 = 0; i2 < 4; ++i2) {
        int row2 = qi * 16 + i2 * 4 + g;
        const ushort* pr = &Pw[row2 * 72 + r16 * 4];
        f32x4 pv = {b2f(pr[0]), b2f(pr[1]), b2f(pr[2]), b2f(pr[3])};
        __builtin_nontemporal_store(
            pv, (f32x4*)&attn[(headQ + q0 + row2) * 2048 + kt * 64 + r16 * 4]);
      }
    if (kt < 31) {
      // counted vmcnt: retire prev-tile stores + this tile's 4 GLDS; leave
      // the newest 8 nt-stores in flight across the barrier.
      asm volatile("s_waitcnt vmcnt(8)" ::: "memory");
      __builtin_amdgcn_s_barrier();
      __builtin_amdgcn_sched_barrier(0);
    }
    cur ^= 1;
  }

  const int b = bh >> 4, h = bh & 15;
#pragma unroll
  for (int qi = 0; qi < 2; ++qi)
#pragma unroll
    for (int dc = 0; dc < 4; ++dc)
#pragma unroll
      for (int r = 0; r < 4; ++r)
        Op[((size_t)(b * 2048 + q0 + qi * 16 + g * 4 + r)) * 1024 + h * 64 +
           dc * 16 + r16] = f2b(o[qi][dc][r]);
}

// ---------------------------------------------------------------------------
extern "C" void kernel_launch(void* const* d_in, const int* in_sizes, int n_in,
                              void* d_out, int out_size, void* d_ws,
                              size_t ws_size, hipStream_t stream) {
  const float* q = (const float*)d_in[0];
  const float* k = (const float*)d_in[1];
  const float* v = (const float*)d_in[2];
  const float* w_qs = (const float*)d_in[3];
  const float* w_ks = (const float*)d_in[4];
  const float* w_vs = (const float*)d_in[5];
  const float* w_fc = (const float*)d_in[6];
  float* out = (float*)d_out;
  float* attn = out + (size_t)4096 * 1024;

  const size_t MB = 1024 * 1024;
  uint8_t* ws = (uint8_t*)d_ws;
  ushort* Qh = (ushort*)(ws + 0 * MB);   // [32][2048][64] bf16
  ushort* Kh = (ushort*)(ws + 8 * MB);   // [32][2048][64]
  ushort* Vt = (ushort*)(ws + 16 * MB);  // [32][64][2048]
  ushort* Op = (ushort*)(ws + 24 * MB);  // [4096][1024]
  ushort* Wq = (ushort*)(ws + 56 * MB);  // [1024 out][1024 in]
  ushort* Wk = (ushort*)(ws + 58 * MB);
  ushort* Wv = (ushort*)(ws + 60 * MB);
  ushort* Wf = (ushort*)(ws + 62 * MB);

  k_trcvt4<<<dim3(32, 32, 4), 256, 0, stream>>>(w_qs, w_ks, w_vs, w_fc, Wq, Wk,
                                                Wv, Wf);
  k_gemm_qkv<<<dim3(256, 3), 256, 0, stream>>>(q, k, v, Wq, Wk, Wv, Qh, Kh,
                                               Vt);
  k_attn_fused<<<512, 256, 0, stream>>>(Qh, Kh, Vt, attn, Op);
  k_gemm_fc<<<dim3(64, 8), 256, 0, stream>>>(Op, Wf, out);
}